// Round 15
// baseline (314.478 us; speedup 1.0000x reference)
//
#include <hip/hip_runtime.h>

#define NB 32
#define NC 3
#define NK 64
#define KS 7
#define IH 224
#define IW 224
#define OH 218
#define OW 218
#define OHW (OH * OW)
#define ROWS 8        // output rows per block (per-row double-buffered, per-wave)

typedef float  f32x4  __attribute__((ext_vector_type(4)));
typedef float  f32x16 __attribute__((ext_vector_type(16)));
typedef short  s16x8  __attribute__((ext_vector_type(8)));
typedef unsigned long long u64;

static __device__ __forceinline__ unsigned short f2bf(float f) {
  unsigned int u = __float_as_uint(f);
  u += 0x7FFFu + ((u >> 16) & 1u);
  return (unsigned short)(u >> 16);
}

// Rotation swizzle on a 32-u16 (64 B) row: 16B-block p = (blk + (t>>2)) & 3.
static __device__ __forceinline__ int swz2(int t, int ci) {
  return ((((ci >> 3) + (t >> 2)) & 3) << 3) | (ci & 7);
}

// ---------------- prep kernels ----------------

// fused: x -> bf16, s = sum_c x^2 (LDS), row box -> t[b][h][ow]
__global__ void k_prep_xrow(const float* __restrict__ x, unsigned short* __restrict__ xb,
                            float* __restrict__ t) {
  __shared__ float s_lds[IW];
  const int n  = blockIdx.x;          // NB*IH
  const int b  = n / IH;
  const int h  = n - b * IH;
  const int px = threadIdx.x;
  if (px < IW) {
    float acc = 0.f;
#pragma unroll
    for (int c = 0; c < NC; ++c) {
      size_t idx = ((size_t)(b * NC + c) * IH + h) * IW + px;
      float v = x[idx];
      xb[idx] = f2bf(v);
      acc += v * v;
    }
    s_lds[px] = acc;
  }
  __syncthreads();
  if (px < OW) {
    float acc = 0.f;
#pragma unroll
    for (int j = 0; j < KS; ++j) acc += s_lds[px + j];
    t[(size_t)(b * IH + h) * OW + px] = acc;
  }
}

// WTg LINEAR: WTg[(j*64+k)*32 + ci] = bf16(memes[k][c][i][j]), ci=c*7+i (<21),
// zeros at 21..31. A-fragments are consumed straight from global (registers).
__global__ void k_prep_w(const float* __restrict__ memes, unsigned short* __restrict__ WTg,
                         float* __restrict__ m2inv) {
  __shared__ float red[3];
  const int k = blockIdx.x, t = threadIdx.x;
  float v = 0.f;
  if (t < 147) v = memes[k * 147 + t];
  float s = v * v;
#pragma unroll
  for (int sh = 32; sh > 0; sh >>= 1) s += __shfl_down(s, sh, 64);
  if ((t & 63) == 0) red[t >> 6] = s;
  __syncthreads();
  if (t == 0) m2inv[k] = 1.0f / (red[0] + red[1] + red[2]);
  if (t < 147) {
    int c = t / 49, rem = t - 49 * c, i = rem / 7, j = rem - 7 * i;
    WTg[(j * NK + k) * 32 + (c * 7 + i)] = f2bf(v);
  }
  for (int idx = t; idx < 7 * 11; idx += 192) {
    int j = idx / 11, ci = 21 + (idx - 11 * j);
    WTg[(j * NK + k) * 32 + ci] = 0;
  }
}

// ---------------- wave-private staging (no cross-wave sharing) ---------------
// One wave-row = 21 ci x 10 px-quads (u64 = 4 px, 40 px incl halo) = 210 slots
// over 64 lanes * 4. Unguarded overreads stay inside ws (finite bits).
static __device__ __forceinline__ void xtw_issue(u64 v[4],
    const unsigned short* __restrict__ xb, int b, int oh, int owb, int lane) {
#pragma unroll
  for (int m = 0; m < 4; ++m) {
    int idx = lane + 64 * m;
    u64 val = 0;
    if (idx < 210) {
      int ci = idx / 10;
      int q  = idx - 10 * ci;
      int c  = ci / 7;
      int i  = ci - 7 * c;
      val = *(const u64*)&xb[((size_t)(b * NC + c) * IH + oh + i) * IW + owb + 4 * q];
    }
    v[m] = val;
  }
}

static __device__ __forceinline__ void xtw_write(unsigned short* __restrict__ XT,
    const u64 v[4], int lane) {
#pragma unroll
  for (int m = 0; m < 4; ++m) {
    int idx = lane + 64 * m;
    if (idx < 210) {
      int ci = idx / 10;
      int q  = idx - 10 * ci;
#pragma unroll
      for (int e = 0; e < 4; ++e) {
        int t = 4 * q + e;               // local row 0..39
        XT[t * 32 + swz2(t, ci)] = (unsigned short)(v[m] >> (16 * e));
      }
    }
  }
}

// ---------------- main MFMA kernel (32x32x16, BARRIER-FREE) ------------------
// Block: 256 thr (4 waves). Wave = (k-half, px-half) quadrant with its OWN
// private double-buffered XT slice (40 rows incl halo). ZERO s_barrier in the
// kernel: 12 waves/CU drift freely, overlapping stage/MFMA/store phases.
__global__ __launch_bounds__(256, 3) void k_main(
    const unsigned short* __restrict__ xb, const float* __restrict__ tg,
    const unsigned short* __restrict__ WTg, const float* __restrict__ m2inv,
    float* __restrict__ out) {
  __shared__ __align__(16) unsigned short XTw[4][2][40 * 32];  // 20480 B

  const int tid  = threadIdx.x;
  const int w    = tid >> 6;
  const int lane = tid & 63;
  const int l31  = lane & 31;
  const int hsel = lane >> 5;       // 0/1: ci-slice / k-subrow group
  const int kh   = w >> 1;          // k-half (0: k 0..31, 1: k 32..63)
  const int ph   = w & 1;           // px-half (0: px 0..31, 1: 32..63)

  // XCD-chunked bijective swizzle: 3584 blocks = 8 XCD x 448.
  const int wg  = blockIdx.x;
  const int sw  = (wg & 7) * 448 + (wg >> 3);
  const int ow0 = (sw & 3) * 64;
  const int ohb = ((sw >> 2) % 28) * ROWS;
  const int b   = sw / 112;

  const int owb = ow0 + ph * 32;    // this wave's image-col staging base

  // A fragments into 56 VGPRs, loaded ONCE per block (L2-hot linear WTg).
  s16x8 Af0[KS], Af1[KS];
  {
    const unsigned short* ap = WTg + (size_t)(kh * 32 + l31) * 32 + hsel * 8;
#pragma unroll
    for (int j = 0; j < KS; ++j) {
      Af0[j] = *(const s16x8*)&ap[(size_t)j * (NK * 32)];
      Af1[j] = *(const s16x8*)&ap[(size_t)j * (NK * 32) + 16];
    }
  }

  // m2 in 16 regs: k = kh*32 + 4*hsel + 8*g + (reg&3)
  f32x4 m2r[4];
  {
    const float* mp = m2inv + kh * 32 + 4 * hsel;
#pragma unroll
    for (int g = 0; g < 4; ++g) m2r[g] = *(const f32x4*)&mp[8 * g];
  }

  unsigned short* myXT[2] = {&XTw[w][0][0], &XTw[w][1][0]};

  // zero pad lanes ci=21..31 in my OWN buffers (own-wave lgkm ordering suffices)
  for (int idx = lane; idx < 2 * 40; idx += 64) {
    int bb = idx / 40, t = idx - 40 * bb;
    unsigned short* row = myXT[bb] + t * 32;
    const int m = (t >> 2) & 3;
    *(uint4*)&row[((3 + m) & 3) << 3] = (uint4){0, 0, 0, 0};   // ci 24..31
    const int b2 = ((2 + m) & 3) << 3;                          // ci 21..23
    row[b2 + 5] = 0; row[b2 + 6] = 0; row[b2 + 7] = 0;
  }

  u64 s0[4];
  xtw_issue(s0, xb, b, ohb, owb, lane);
  xtw_write(myXT[0], s0, lane);     // compiler orders vm/lgkm waits per-wave

  const int ow = owb + l31;

#pragma unroll 1
  for (int r = 0; r < ROWS; ++r) {
    const int oh = ohb + r;
    const bool more = (r + 1 < ROWS);

    u64 sn[4];
    if (more) xtw_issue(sn, xb, b, oh + 1, owb, lane);  // loads fly over MFMAs

    const bool ok = (ow < OW) && (oh < OH);

    // x2 on the fly (colbox fused): 7 L2-hot loads overlap the MFMAs below
    float x2v = 0.f;
    if (ok) {
      const float* tp = tg + ((size_t)b * IH + oh) * OW + ow;
#pragma unroll
      for (int i = 0; i < KS; ++i) x2v += tp[i * OW];
    }

    const unsigned short* XT = myXT[r & 1];
    f32x16 accA = {0.f,0.f,0.f,0.f,0.f,0.f,0.f,0.f,0.f,0.f,0.f,0.f,0.f,0.f,0.f,0.f};
    f32x16 accB = accA;

#pragma unroll
    for (int j = 0; j < KS; ++j) {
      const int t = l31 + j;                 // local row in my slice
      const unsigned short* br = XT + t * 32;
      const int m = (t >> 2) & 3;
      s16x8 bA = *(const s16x8*)&br[((hsel + m) & 3) << 3];        // ci slice hsel
      s16x8 bB = *(const s16x8*)&br[((2 + hsel + m) & 3) << 3];    // ci slice 2+hsel
      accA = __builtin_amdgcn_mfma_f32_32x32x16_bf16(Af0[j], bA, accA, 0, 0, 0);
      accB = __builtin_amdgcn_mfma_f32_32x32x16_bf16(Af1[j], bB, accB, 0, 0, 0);
    }
    const f32x16 acc = accA + accB;

    // exec-masked stores: invalid lanes are masked off (free).
    if (ok) {
      float* ob = out + ((size_t)(b * NK + kh * 32) * OH + oh) * OW + ow;
#pragma unroll
      for (int reg = 0; reg < 16; ++reg) {
        const int kk = (reg & 3) + 8 * (reg >> 2) + 4 * hsel;
        ob[(size_t)kk * OHW] = (x2v - 2.0f * acc[reg]) * m2r[reg >> 2][reg & 3] + 1.0f;
      }
    }

    if (more) xtw_write(myXT[(r + 1) & 1], sn, lane);  // own buffer: no hazard
  }
}

// ---------------- launch ----------------
extern "C" void kernel_launch(void* const* d_in, const int* in_sizes, int n_in,
                              void* d_out, int out_size, void* d_ws, size_t ws_size,
                              hipStream_t stream) {
  const float* x     = (const float*)d_in[0];   // [32,3,224,224]
  const float* memes = (const float*)d_in[1];   // [64,3,7,7]
  float* out = (float*)d_out;                   // [32,64,218,218]

  char* ws = (char*)d_ws;
  unsigned short* xb  = (unsigned short*)(ws);                 // 9,633,792 B
  float* t            = (float*)(ws + 9633792);                // 6,250,496 B
  unsigned short* WTg = (unsigned short*)(ws + 15884288);      // 28,672 B
  float* m2inv        = (float*)(ws + 15912960);               // 256 B

  (void)in_sizes; (void)n_in; (void)out_size; (void)ws_size;

  k_prep_xrow<<<NB * IH, 256, 0, stream>>>(x, xb, t);
  k_prep_w<<<NK, 192, 0, stream>>>(memes, WTg, m2inv);

  // 3584 blocks = 4 ow-tiles x 28 oh-blocks x 32 b, flattened for XCD swizzle
  k_main<<<4 * 28 * NB, 256, 0, stream>>>(xb, t, WTg, m2inv, out);
}

// Round 16
// 150.884 us; speedup vs baseline: 2.0842x; 2.0842x over previous
//
#include <hip/hip_runtime.h>

#define NB 32
#define NC 3
#define NK 64
#define KS 7
#define IH 224
#define IW 224
#define OH 218
#define OW 218
#define OHW (OH * OW)
#define ROWS 8        // output rows per block (per-row double-buffered)

typedef float  f32x4  __attribute__((ext_vector_type(4)));
typedef float  f32x16 __attribute__((ext_vector_type(16)));
typedef short  s16x8  __attribute__((ext_vector_type(8)));
typedef unsigned long long u64;

static __device__ __forceinline__ unsigned short f2bf(float f) {
  unsigned int u = __float_as_uint(f);
  u += 0x7FFFu + ((u >> 16) & 1u);
  return (unsigned short)(u >> 16);
}

// Rotation swizzle on a 32-u16 (64 B) row: 16B-block p = (blk + (t>>2)) & 3.
// Staging writes (lane stride = 4 rows) spread over 4 bank-quads; fragment
// reads (lane stride = 1 row) see 4-lane groups per quad -> ~2-way (free).
static __device__ __forceinline__ int swz2(int t, int ci) {
  return ((((ci >> 3) + (t >> 2)) & 3) << 3) | (ci & 7);
}

// ---------------- prep kernels ----------------

// fused: x -> bf16, s = sum_c x^2 (LDS), row box -> t[b][h][ow]
__global__ void k_prep_xrow(const float* __restrict__ x, unsigned short* __restrict__ xb,
                            float* __restrict__ t) {
  __shared__ float s_lds[IW];
  const int n  = blockIdx.x;          // NB*IH
  const int b  = n / IH;
  const int h  = n - b * IH;
  const int px = threadIdx.x;
  if (px < IW) {
    float acc = 0.f;
#pragma unroll
    for (int c = 0; c < NC; ++c) {
      size_t idx = ((size_t)(b * NC + c) * IH + h) * IW + px;
      float v = x[idx];
      xb[idx] = f2bf(v);
      acc += v * v;
    }
    s_lds[px] = acc;
  }
  __syncthreads();
  if (px < OW) {
    float acc = 0.f;
#pragma unroll
    for (int j = 0; j < KS; ++j) acc += s_lds[px + j];
    t[(size_t)(b * IH + h) * OW + px] = acc;
  }
}

// WTg LINEAR: WTg[(j*64+k)*32 + ci] = bf16(memes[k][c][i][j]), ci=c*7+i (<21),
// zeros at 21..31. A-fragments are consumed straight from global (registers).
__global__ void k_prep_w(const float* __restrict__ memes, unsigned short* __restrict__ WTg,
                         float* __restrict__ m2inv) {
  __shared__ float red[3];
  const int k = blockIdx.x, t = threadIdx.x;
  float v = 0.f;
  if (t < 147) v = memes[k * 147 + t];
  float s = v * v;
#pragma unroll
  for (int sh = 32; sh > 0; sh >>= 1) s += __shfl_down(s, sh, 64);
  if ((t & 63) == 0) red[t >> 6] = s;
  __syncthreads();
  if (t == 0) m2inv[k] = 1.0f / (red[0] + red[1] + red[2]);
  if (t < 147) {
    int c = t / 49, rem = t - 49 * c, i = rem / 7, j = rem - 7 * i;
    WTg[(j * NK + k) * 32 + (c * 7 + i)] = f2bf(v);
  }
  for (int idx = t; idx < 7 * 11; idx += 192) {
    int j = idx / 11, ci = 21 + (idx - 11 * j);
    WTg[(j * NK + k) * 32 + ci] = 0;
  }
}

// ---------------- per-row staging (issue-early / write-late) ----------------
// One row = 21 ci x 18 tq (u64 = 4 px) = 378 slots over 256 threads * 2.
static __device__ __forceinline__ void xt_issue(u64 v[2],
    const unsigned short* __restrict__ xb, int b, int oh, int ow0, int tid) {
#pragma unroll
  for (int m = 0; m < 2; ++m) {
    int idx = tid + 256 * m;
    u64 val = 0;
    if (idx < 378) {
      int tq = idx % 18;
      int ci = idx / 18;
      int c  = ci / 7;
      int i  = ci - 7 * c;
      // unguarded: overreads stay inside ws (finite bits), feed only masked lanes
      val = *(const u64*)&xb[((size_t)(b * NC + c) * IH + oh + i) * IW + ow0 + 4 * tq];
    }
    v[m] = val;
  }
}

static __device__ __forceinline__ void xt_write(unsigned short* __restrict__ XT,
    const u64 v[2], int tid) {
#pragma unroll
  for (int m = 0; m < 2; ++m) {
    int idx = tid + 256 * m;
    if (idx < 378) {
      int tq = idx % 18;
      int ci = idx / 18;
#pragma unroll
      for (int e = 0; e < 4; ++e) {
        int t = 4 * tq + e;
        XT[t * 32 + swz2(t, ci)] = (unsigned short)(v[m] >> (16 * e));
      }
    }
  }
}

// ---------------- main MFMA kernel (32x32x16, A in regs, LDS = XT only) -----
// Block: 256 thr (4 waves). Wave = (k-half, px-half) quadrant.
// Proven r13 configuration: __launch_bounds__(256,3), A-fragments resident.
__global__ __launch_bounds__(256, 3) void k_main(
    const unsigned short* __restrict__ xb, const float* __restrict__ tg,
    const unsigned short* __restrict__ WTg, const float* __restrict__ m2inv,
    float* __restrict__ out) {
  __shared__ __align__(16) unsigned short XTl[2][72 * 32];     // 9216 B total LDS

  const int tid  = threadIdx.x;
  const int w    = tid >> 6;
  const int lane = tid & 63;
  const int l31  = lane & 31;
  const int hsel = lane >> 5;       // 0/1: ci-slice / k-subrow group
  const int kh   = w >> 1;          // k-half (0: k 0..31, 1: k 32..63)
  const int ph   = w & 1;           // px-half (0: px 0..31, 1: 32..63)

  // XCD-chunked bijective swizzle: 3584 blocks = 8 XCD x 448.
  const int wg  = blockIdx.x;
  const int sw  = (wg & 7) * 448 + (wg >> 3);
  const int ow0 = (sw & 3) * 64;
  const int ohb = ((sw >> 2) % 28) * ROWS;
  const int b   = sw / 112;

  // A fragments into 56 VGPRs, loaded ONCE per block (L2-hot linear WTg).
  // Row = j*64 + kh*32 + l31; Af0 = ci slice hsel, Af1 = ci slice 2+hsel.
  s16x8 Af0[KS], Af1[KS];
  {
    const unsigned short* ap = WTg + (size_t)(kh * 32 + l31) * 32 + hsel * 8;
#pragma unroll
    for (int j = 0; j < KS; ++j) {
      Af0[j] = *(const s16x8*)&ap[(size_t)j * (NK * 32)];
      Af1[j] = *(const s16x8*)&ap[(size_t)j * (NK * 32) + 16];
    }
  }

  // m2 in 16 regs: k = kh*32 + 4*hsel + 8*g + (reg&3)
  f32x4 m2r[4];
  {
    const float* mp = m2inv + kh * 32 + 4 * hsel;
#pragma unroll
    for (int g = 0; g < 4; ++g) m2r[g] = *(const f32x4*)&mp[8 * g];
  }

  // zero pad lanes ci=21..31 in BOTH buffers (MFMA reads them; 0*NaN=NaN!)
  for (int idx = tid; idx < 2 * 72; idx += 256) {
    int bb = idx / 72, t = idx - 72 * bb;
    unsigned short* row = &XTl[bb][t * 32];
    const int m = (t >> 2) & 3;
    *(uint4*)&row[((3 + m) & 3) << 3] = (uint4){0, 0, 0, 0};   // ci 24..31
    const int b2 = ((2 + m) & 3) << 3;                          // ci 21..23
    row[b2 + 5] = 0; row[b2 + 6] = 0; row[b2 + 7] = 0;
  }

  u64 s0[2];
  xt_issue(s0, xb, b, ohb, ow0, tid);
  xt_write(&XTl[0][0], s0, tid);
  asm volatile("s_waitcnt lgkmcnt(0)" ::: "memory");
  __builtin_amdgcn_s_barrier();

  const int tB = ph * 32 + l31;     // this lane's px within the 64-tile
  const int ow = ow0 + tB;

#pragma unroll 1
  for (int r = 0; r < ROWS; ++r) {
    const int oh = ohb + r;
    const bool more = (r + 1 < ROWS);

    u64 sn[2];
    if (more) xt_issue(sn, xb, b, oh + 1, ow0, tid);   // loads fly over MFMAs

    const bool ok = (ow < OW) && (oh < OH);

    // x2 on the fly (colbox fused): 7 L2-hot loads overlap the MFMAs below
    float x2v = 0.f;
    if (ok) {
      const float* tp = tg + ((size_t)b * IH + oh) * OW + ow;
#pragma unroll
      for (int i = 0; i < KS; ++i) x2v += tp[i * OW];
    }

    const unsigned short* XT = &XTl[r & 1][0];
    f32x16 accA = {0.f,0.f,0.f,0.f,0.f,0.f,0.f,0.f,0.f,0.f,0.f,0.f,0.f,0.f,0.f,0.f};
    f32x16 accB = accA;

#pragma unroll
    for (int j = 0; j < KS; ++j) {
      const int t = tB + j;
      const unsigned short* br = XT + t * 32;
      const int m = (t >> 2) & 3;
      s16x8 bA = *(const s16x8*)&br[((hsel + m) & 3) << 3];        // ci slice hsel
      s16x8 bB = *(const s16x8*)&br[((2 + hsel + m) & 3) << 3];    // ci slice 2+hsel
      accA = __builtin_amdgcn_mfma_f32_32x32x16_bf16(Af0[j], bA, accA, 0, 0, 0);
      accB = __builtin_amdgcn_mfma_f32_32x32x16_bf16(Af1[j], bB, accB, 0, 0, 0);
    }
    const f32x16 acc = accA + accB;

    // exec-masked stores: invalid lanes are masked off (free).
    // C/D: col = lane&31 (=px), k = kh*32 + (reg&3) + 8*(reg>>2) + 4*hsel.
    if (ok) {
      float* ob = out + ((size_t)(b * NK + kh * 32) * OH + oh) * OW + ow;
#pragma unroll
      for (int reg = 0; reg < 16; ++reg) {
        const int kk = (reg & 3) + 8 * (reg >> 2) + 4 * hsel;
        ob[(size_t)kk * OHW] = (x2v - 2.0f * acc[reg]) * m2r[reg >> 2][reg & 3] + 1.0f;
      }
    }

    if (more) {
      xt_write(&XTl[(r + 1) & 1][0], sn, tid);  // other-parity buffer: no hazard
      asm volatile("s_waitcnt lgkmcnt(0)" ::: "memory");
      __builtin_amdgcn_s_barrier();             // single barrier per row
    }
  }
}

// ---------------- launch ----------------
extern "C" void kernel_launch(void* const* d_in, const int* in_sizes, int n_in,
                              void* d_out, int out_size, void* d_ws, size_t ws_size,
                              hipStream_t stream) {
  const float* x     = (const float*)d_in[0];   // [32,3,224,224]
  const float* memes = (const float*)d_in[1];   // [64,3,7,7]
  float* out = (float*)d_out;                   // [32,64,218,218]

  char* ws = (char*)d_ws;
  unsigned short* xb  = (unsigned short*)(ws);                 // 9,633,792 B
  float* t            = (float*)(ws + 9633792);                // 6,250,496 B
  unsigned short* WTg = (unsigned short*)(ws + 15884288);      // 28,672 B
  float* m2inv        = (float*)(ws + 15912960);               // 256 B

  (void)in_sizes; (void)n_in; (void)out_size; (void)ws_size;

  k_prep_xrow<<<NB * IH, 256, 0, stream>>>(x, xb, t);
  k_prep_w<<<NK, 192, 0, stream>>>(memes, WTg, m2inv);

  // 3584 blocks = 4 ow-tiles x 28 oh-blocks x 32 b, flattened for XCD swizzle
  k_main<<<4 * 28 * NB, 256, 0, stream>>>(xb, t, WTg, m2inv, out);
}